// Round 1
// baseline (340.934 us; speedup 1.0000x reference)
//
#include <hip/hip_runtime.h>
#include <hip/hip_bf16.h>
#include <stdint.h>

#define NUM_NODES 100000
#define NUM_EDGES 50000
#define NUM_CONN  800000
#define IN_DIM    256
#define HIDDEN    128
#define EDGE_DIM  17
#define PAD       64
#define KPAD      264   /* IN_DIM + 8 halves: breaks power-of-2 LDS stride */

typedef __bf16 bf16x8 __attribute__((ext_vector_type(8)));
typedef float  f32x4  __attribute__((ext_vector_type(4)));

// ---------------- ws layout ----------------
// P     : bf16 [NUM_NODES][HIDDEN]        25,600,000 B @ 0
// W1T   : bf16 [HIDDEN][KPAD]                 67,584 B @ 25,600,000
// counts: int  [NUM_EDGES]                   200,000 B @ 25,667,584
// slots : int  [NUM_EDGES][PAD]           12,800,000 B @ 25,867,584
// total ~38.7 MB

__global__ void prep_kernel(const float* __restrict__ W1,
                            __bf16* __restrict__ w1t,
                            int* __restrict__ counts) {
    int i = blockIdx.x * 256 + threadIdx.x;
    if (i < NUM_EDGES) counts[i] = 0;
    if (i < IN_DIM * HIDDEN) {
        int k = i / HIDDEN, n = i % HIDDEN;
        w1t[n * KPAD + k] = (__bf16)W1[i];   // W1T[n][k] = W1[k][n]
    }
}

__global__ void bucket_kernel(const int* __restrict__ idx, int stride,
                              int* __restrict__ counts, int* __restrict__ slots) {
    int i = blockIdx.x * 256 + threadIdx.x;   // grid covers NUM_CONN exactly
    int node = idx[(size_t)i * stride];
    int edge = idx[((size_t)(NUM_CONN + i)) * stride];
    int pos = atomicAdd(&counts[edge], 1);
    if (pos < PAD) slots[(size_t)edge * PAD + pos] = node;
}

// P[m][n] = sum_k nf[m][k] * W1[k][n]; bf16 MFMA 16x16x32, fp32 accumulate.
__global__ __launch_bounds__(256) void proj_kernel(const float* __restrict__ nf,
                                                   const __bf16* __restrict__ w1t,
                                                   __bf16* __restrict__ pbf) {
    __shared__ __align__(16) __bf16 lds_w[HIDDEN * KPAD];   // 67,584 B
    {   // stage whole W1T (bf16, padded) into LDS once per block
        const uint4* src = (const uint4*)w1t;
        uint4* dst = (uint4*)lds_w;
        const int NV = HIDDEN * KPAD * 2 / 16;   // 4224 x 16B
        for (int i = threadIdx.x; i < NV; i += 256) dst[i] = src[i];
    }
    __syncthreads();

    const int wave = threadIdx.x >> 6;
    const int lane = threadIdx.x & 63;
    const int m = lane & 15;        // A row within 16-tile / C col
    const int q = lane >> 4;        // quad
    const int row = blockIdx.x * 64 + wave * 16 + m;
    const int arow = row < NUM_NODES ? row : NUM_NODES - 1;  // clamp, store-guarded
    const float* aptr = nf + (size_t)arow * IN_DIM + q * 8;

    f32x4 acc[8];
    #pragma unroll
    for (int t = 0; t < 8; ++t) acc[t] = (f32x4){0.f, 0.f, 0.f, 0.f};

    #pragma unroll
    for (int kk = 0; kk < IN_DIM; kk += 32) {
        float4 af0 = *(const float4*)(aptr + kk);
        float4 af1 = *(const float4*)(aptr + kk + 4);
        bf16x8 a;
        a[0] = (__bf16)af0.x; a[1] = (__bf16)af0.y;
        a[2] = (__bf16)af0.z; a[3] = (__bf16)af0.w;
        a[4] = (__bf16)af1.x; a[5] = (__bf16)af1.y;
        a[6] = (__bf16)af1.z; a[7] = (__bf16)af1.w;
        #pragma unroll
        for (int t = 0; t < 8; ++t) {
            bf16x8 b = *(const bf16x8*)&lds_w[(t * 16 + m) * KPAD + kk + q * 8];
            acc[t] = __builtin_amdgcn_mfma_f32_16x16x32_bf16(a, b, acc[t], 0, 0, 0);
        }
    }

    // C/D layout: col = lane&15, row = quad*4 + reg  [verified mapping]
    const int orow_base = blockIdx.x * 64 + wave * 16 + q * 4;
    #pragma unroll
    for (int t = 0; t < 8; ++t) {
        #pragma unroll
        for (int r = 0; r < 4; ++r) {
            int orow = orow_base + r;
            if (orow < NUM_NODES)
                pbf[(size_t)orow * HIDDEN + t * 16 + m] = (__bf16)acc[t][r];
        }
    }
}

// One wave per edge: gather-mean P rows, +b1, LayerNorm, ReLU, @W2 + b2.
__global__ __launch_bounds__(256) void edge_kernel(const uint32_t* __restrict__ pbf,
        const int* __restrict__ counts, const int* __restrict__ slots,
        const float* __restrict__ b1, const float* __restrict__ ln_g,
        const float* __restrict__ ln_b, const float* __restrict__ W2,
        const float* __restrict__ b2, float* __restrict__ out) {
    const int wave = threadIdx.x >> 6;
    const int lane = threadIdx.x & 63;
    const int e = blockIdx.x * 4 + wave;

    const int c = counts[e];
    const int cc = c < PAD ? c : PAD;
    const float inv = 1.0f / (float)(c > 0 ? c : 1);
    const int* sl = slots + (size_t)e * PAD;

    float a0 = 0.f, a1 = 0.f;   // lane owns hidden dims 2*lane, 2*lane+1
    for (int j = 0; j < cc; ++j) {
        int nd = sl[j];
        uint32_t u = pbf[(size_t)nd * 64 + lane];   // 2 bf16, coalesced 256B/row
        a0 += __uint_as_float(u << 16);
        a1 += __uint_as_float(u & 0xffff0000u);
    }
    float h0 = a0 * inv + b1[2 * lane];
    float h1 = a1 * inv + b1[2 * lane + 1];

    float s = h0 + h1;
    #pragma unroll
    for (int off = 32; off > 0; off >>= 1) s += __shfl_xor(s, off, 64);
    float mu = s * (1.0f / 128.0f);
    float d0 = h0 - mu, d1 = h1 - mu;
    float v = d0 * d0 + d1 * d1;
    #pragma unroll
    for (int off = 32; off > 0; off >>= 1) v += __shfl_xor(v, off, 64);
    float rs = rsqrtf(v * (1.0f / 128.0f) + 1e-5f);

    float r0 = d0 * rs * ln_g[2 * lane] + ln_b[2 * lane];
    float r1 = d1 * rs * ln_g[2 * lane + 1] + ln_b[2 * lane + 1];
    r0 = r0 > 0.f ? r0 : 0.f;
    r1 = r1 > 0.f ? r1 : 0.f;

    float p[EDGE_DIM];
    const float* w2a = W2 + (2 * lane) * EDGE_DIM;
    const float* w2b = W2 + (2 * lane + 1) * EDGE_DIM;
    #pragma unroll
    for (int j = 0; j < EDGE_DIM; ++j) p[j] = r0 * w2a[j] + r1 * w2b[j];
    #pragma unroll
    for (int j = 0; j < EDGE_DIM; ++j) {
        #pragma unroll
        for (int off = 32; off > 0; off >>= 1) p[j] += __shfl_xor(p[j], off, 64);
    }
    if (lane == 0) {
        float* o = out + (size_t)e * EDGE_DIM;
        #pragma unroll
        for (int j = 0; j < EDGE_DIM; ++j) o[j] = p[j] + b2[j];
    }
}

extern "C" void kernel_launch(void* const* d_in, const int* in_sizes, int n_in,
                              void* d_out, int out_size, void* d_ws, size_t ws_size,
                              hipStream_t stream) {
    const float* nf  = (const float*)d_in[0];
    const int*   idx = (const int*)d_in[1];
    const float* W1  = (const float*)d_in[2];
    const float* b1  = (const float*)d_in[3];
    const float* g   = (const float*)d_in[4];
    const float* be  = (const float*)d_in[5];
    const float* W2  = (const float*)d_in[6];
    const float* b2  = (const float*)d_in[7];
    float* out = (float*)d_out;

    char* ws = (char*)d_ws;
    __bf16* P      = (__bf16*)ws;
    __bf16* W1T    = (__bf16*)(ws + 25600000);
    int*    counts = (int*)(ws + 25600000 + 67584);
    int*    slots  = (int*)(ws + 25600000 + 67584 + (size_t)NUM_EDGES * 4);

    // int64 indices arrive as 2x int32 little-endian words; int32 as-is
    int stride = (in_sizes[1] == 2 * NUM_CONN) ? 1 : 2;

    prep_kernel<<<(NUM_EDGES + 255) / 256, 256, 0, stream>>>(W1, W1T, counts);
    bucket_kernel<<<NUM_CONN / 256, 256, 0, stream>>>(idx, stride, counts, slots);
    proj_kernel<<<(NUM_NODES + 63) / 64, 256, 0, stream>>>(nf, W1T, P);
    edge_kernel<<<NUM_EDGES / 4, 256, 0, stream>>>((const uint32_t*)P, counts, slots,
                                                   b1, g, be, W2, b2, out);
}

// Round 2
// 299.834 us; speedup vs baseline: 1.1371x; 1.1371x over previous
//
#include <hip/hip_runtime.h>
#include <hip/hip_bf16.h>
#include <stdint.h>

#define NUM_NODES 100000
#define NUM_EDGES 50000
#define NUM_CONN  800000
#define IN_DIM    256
#define HIDDEN    128
#define EDGE_DIM  17
#define PAD       64

typedef __bf16 bf16x8 __attribute__((ext_vector_type(8)));
typedef float  f32x4  __attribute__((ext_vector_type(4)));

// ---------------- ws layout ----------------
// P     : bf16 [NUM_NODES][HIDDEN]   25,600,000 B @ 0
// counts: int  [NUM_EDGES]              200,000 B @ 25,600,000
// slots : int  [NUM_EDGES][PAD]      12,800,000 B @ 25,800,000
// W1F   : bf16 frag-major [8][8][64][8]  65,536 B @ 38,600,000

// Pack W1 (fp32 [K=256][N=128]) into MFMA B-fragment-major bf16 layout:
// W1F[kc2][t][lane][ki] = W1[kc2*32 + (lane>>4)*8 + ki][t*16 + (lane&15)]
// so proj's B-read is lds + (kc2*8+t)*64*16 + lane*16 — contiguous, conflict-free.
__global__ void pack_w1_kernel(const float* __restrict__ W1, __bf16* __restrict__ w1f) {
    int i = blockIdx.x * 256 + threadIdx.x;   // 4096 fragments of 8 halves
    if (i >= 4096) return;
    int lane = i & 63, t = (i >> 6) & 7, kc2 = i >> 9;
    int m = lane & 15, q = lane >> 4;
    int n = t * 16 + m;
    int kbase = kc2 * 32 + q * 8;
    __bf16* dst = w1f + (size_t)i * 8;
    #pragma unroll
    for (int ki = 0; ki < 8; ++ki)
        dst[ki] = (__bf16)W1[(size_t)(kbase + ki) * HIDDEN + n];
}

__global__ void bucket_kernel(const int* __restrict__ idx, int stride,
                              int* __restrict__ counts, int* __restrict__ slots) {
    int i = blockIdx.x * 256 + threadIdx.x;   // grid covers NUM_CONN exactly
    int node = idx[(size_t)i * stride];
    int edge = idx[((size_t)(NUM_CONN + i)) * stride];
    int pos = atomicAdd(&counts[edge], 1);
    if (pos < PAD) slots[(size_t)edge * PAD + pos] = node;
}

// P[m][n] = sum_k nf[m][k] * W1[k][n]; 4 m-tiles/wave, 256 rows/block.
__global__ __launch_bounds__(256, 2) void proj_kernel(const float* __restrict__ nf,
                                                      const __bf16* __restrict__ w1f,
                                                      __bf16* __restrict__ pbf) {
    __shared__ __align__(16) __bf16 lds[32768];   // 64 KB, fragment-major
    {
        const uint4* s = (const uint4*)w1f;
        uint4* d = (uint4*)lds;
        #pragma unroll 4
        for (int i = threadIdx.x; i < 4096; i += 256) d[i] = s[i];
    }
    __syncthreads();

    const int wave = threadIdx.x >> 6;
    const int lane = threadIdx.x & 63;
    const int m = lane & 15, q = lane >> 4;
    const int rowbase = blockIdx.x * 256 + wave * 64;   // wave owns 64 rows
    const bf16x8* frag = (const bf16x8*)lds;

    f32x4 acc[4][8];
    #pragma unroll
    for (int mt = 0; mt < 4; ++mt)
        #pragma unroll
        for (int t = 0; t < 8; ++t) acc[mt][t] = (f32x4){0.f, 0.f, 0.f, 0.f};

    const float* ap[4];
    #pragma unroll
    for (int mt = 0; mt < 4; ++mt) {
        int r = rowbase + mt * 16 + m;
        if (r >= NUM_NODES) r = NUM_NODES - 1;   // clamp; stores are guarded
        ap[mt] = nf + (size_t)r * IN_DIM + q * 8;
    }

    #pragma unroll
    for (int kc2 = 0; kc2 < 8; ++kc2) {
        bf16x8 b[8];
        #pragma unroll
        for (int t = 0; t < 8; ++t) b[t] = frag[(kc2 * 8 + t) * 64 + lane];
        #pragma unroll
        for (int mt = 0; mt < 4; ++mt) {
            float4 f0 = *(const float4*)(ap[mt] + kc2 * 32);
            float4 f1 = *(const float4*)(ap[mt] + kc2 * 32 + 4);
            bf16x8 a;
            a[0] = (__bf16)f0.x; a[1] = (__bf16)f0.y;
            a[2] = (__bf16)f0.z; a[3] = (__bf16)f0.w;
            a[4] = (__bf16)f1.x; a[5] = (__bf16)f1.y;
            a[6] = (__bf16)f1.z; a[7] = (__bf16)f1.w;
            #pragma unroll
            for (int t = 0; t < 8; ++t)
                acc[mt][t] = __builtin_amdgcn_mfma_f32_16x16x32_bf16(a, b[t], acc[mt][t], 0, 0, 0);
        }
    }

    // C/D layout: col = lane&15, row = q*4 + reg
    #pragma unroll
    for (int mt = 0; mt < 4; ++mt) {
        int ob = rowbase + mt * 16 + q * 4;
        #pragma unroll
        for (int t = 0; t < 8; ++t)
            #pragma unroll
            for (int r = 0; r < 4; ++r) {
                int orow = ob + r;
                if (orow < NUM_NODES)
                    pbf[(size_t)orow * HIDDEN + t * 16 + m] = (__bf16)acc[mt][t][r];
            }
    }
}

// One wave per edge: gather-mean P rows (8-way unrolled for MLP), +b1, LN, ReLU, @W2+b2.
__global__ __launch_bounds__(256) void edge_kernel(const uint32_t* __restrict__ pbf,
        const int* __restrict__ counts, const int* __restrict__ slots,
        const float* __restrict__ b1, const float* __restrict__ ln_g,
        const float* __restrict__ ln_b, const float* __restrict__ W2,
        const float* __restrict__ b2, float* __restrict__ out) {
    const int wave = threadIdx.x >> 6;
    const int lane = threadIdx.x & 63;
    const int e = blockIdx.x * 4 + wave;

    const int c = counts[e];
    const int cc = c < PAD ? c : PAD;
    const float inv = 1.0f / (float)(c > 0 ? c : 1);
    const int* sl = slots + (size_t)e * PAD;

    float a0 = 0.f, a1 = 0.f;   // lane owns hidden dims 2*lane, 2*lane+1
    // j steps by 8 from 0 while j < cc <= 64 -> reads sl[j..j+7] stay within PAD.
    for (int j = 0; j < cc; j += 8) {
        int4 na = *(const int4*)(sl + j);
        int4 nb = *(const int4*)(sl + j + 4);
        int nd[8] = {na.x, na.y, na.z, na.w, nb.x, nb.y, nb.z, nb.w};
        uint32_t u[8];
        #pragma unroll
        for (int k = 0; k < 8; ++k) {
            int n = nd[k];
            n = ((unsigned)n < NUM_NODES) ? n : 0;   // clamp stale slots
            u[k] = pbf[(size_t)n * 64 + lane];        // 8 loads in flight
        }
        #pragma unroll
        for (int k = 0; k < 8; ++k) {
            bool ok = (j + k) < cc;
            a0 += ok ? __uint_as_float(u[k] << 16) : 0.f;
            a1 += ok ? __uint_as_float(u[k] & 0xffff0000u) : 0.f;
        }
    }
    float h0 = a0 * inv + b1[2 * lane];
    float h1 = a1 * inv + b1[2 * lane + 1];

    float s = h0 + h1;
    #pragma unroll
    for (int off = 32; off > 0; off >>= 1) s += __shfl_xor(s, off, 64);
    float mu = s * (1.0f / 128.0f);
    float d0 = h0 - mu, d1 = h1 - mu;
    float v = d0 * d0 + d1 * d1;
    #pragma unroll
    for (int off = 32; off > 0; off >>= 1) v += __shfl_xor(v, off, 64);
    float rs = rsqrtf(v * (1.0f / 128.0f) + 1e-5f);

    float r0 = d0 * rs * ln_g[2 * lane] + ln_b[2 * lane];
    float r1 = d1 * rs * ln_g[2 * lane + 1] + ln_b[2 * lane + 1];
    r0 = r0 > 0.f ? r0 : 0.f;
    r1 = r1 > 0.f ? r1 : 0.f;

    float p[EDGE_DIM];
    const float* w2a = W2 + (2 * lane) * EDGE_DIM;
    const float* w2b = W2 + (2 * lane + 1) * EDGE_DIM;
    #pragma unroll
    for (int j = 0; j < EDGE_DIM; ++j) p[j] = r0 * w2a[j] + r1 * w2b[j];
    #pragma unroll
    for (int j = 0; j < EDGE_DIM; ++j) {
        #pragma unroll
        for (int off = 32; off > 0; off >>= 1) p[j] += __shfl_xor(p[j], off, 64);
    }
    if (lane == 0) {
        float* o = out + (size_t)e * EDGE_DIM;
        #pragma unroll
        for (int j = 0; j < EDGE_DIM; ++j) o[j] = p[j] + b2[j];
    }
}

extern "C" void kernel_launch(void* const* d_in, const int* in_sizes, int n_in,
                              void* d_out, int out_size, void* d_ws, size_t ws_size,
                              hipStream_t stream) {
    const float* nf  = (const float*)d_in[0];
    const int*   idx = (const int*)d_in[1];
    const float* W1  = (const float*)d_in[2];
    const float* b1  = (const float*)d_in[3];
    const float* g   = (const float*)d_in[4];
    const float* be  = (const float*)d_in[5];
    const float* W2  = (const float*)d_in[6];
    const float* b2  = (const float*)d_in[7];
    float* out = (float*)d_out;

    char* ws = (char*)d_ws;
    __bf16* P      = (__bf16*)ws;
    int*    counts = (int*)(ws + 25600000);
    int*    slots  = (int*)(ws + 25800000);
    __bf16* W1F    = (__bf16*)(ws + 38600000);

    int stride = (in_sizes[1] == 2 * NUM_CONN) ? 1 : 2;

    hipMemsetAsync(counts, 0, (size_t)NUM_EDGES * 4, stream);
    pack_w1_kernel<<<16, 256, 0, stream>>>(W1, W1F);
    bucket_kernel<<<NUM_CONN / 256, 256, 0, stream>>>(idx, stride, counts, slots);
    proj_kernel<<<(NUM_NODES + 255) / 256, 256, 0, stream>>>(nf, W1F, P);
    edge_kernel<<<NUM_EDGES / 4, 256, 0, stream>>>((const uint32_t*)P, counts, slots,
                                                   b1, g, be, W2, b2, out);
}

// Round 3
// 276.816 us; speedup vs baseline: 1.2316x; 1.0832x over previous
//
#include <hip/hip_runtime.h>
#include <hip/hip_bf16.h>
#include <stdint.h>

#define NUM_NODES 100000
#define NUM_EDGES 50000
#define NUM_CONN  800000
#define IN_DIM    256
#define HIDDEN    128
#define EDGE_DIM  17
#define PAD       64

typedef __bf16 bf16x8 __attribute__((ext_vector_type(8)));
typedef float  f32x4  __attribute__((ext_vector_type(4)));

// ---------------- ws layout ----------------
// P     : bf16 [NUM_NODES][HIDDEN]   25,600,000 B @ 0
// counts: int  [NUM_EDGES]              200,000 B @ 25,600,000
// slots : int  [NUM_EDGES][PAD]      12,800,000 B @ 25,800,000
// W1F   : bf16 frag-major [8][8][64][8]  65,536 B @ 38,600,000
// W2F   : bf16 frag-major [4][2][64][8]   8,192 B @ 38,665,536
// r     : bf16 [NUM_EDGES][HIDDEN]   12,800,000 B @ 38,673,728
// total ~51.5 MB

// Pack W1 + W2 into MFMA B-fragment-major bf16 layouts (contiguous ds_read_b128).
__global__ void pack_w_kernel(const float* __restrict__ W1, const float* __restrict__ W2,
                              __bf16* __restrict__ w1f, __bf16* __restrict__ w2f) {
    int i = blockIdx.x * 256 + threadIdx.x;
    if (i < 4096) {            // W1F[kc2][t][lane][ki]
        int lane = i & 63, t = (i >> 6) & 7, kc2 = i >> 9;
        int m = lane & 15, q = lane >> 4;
        int n = t * 16 + m;
        int kbase = kc2 * 32 + q * 8;
        __bf16* dst = w1f + (size_t)i * 8;
        #pragma unroll
        for (int ki = 0; ki < 8; ++ki)
            dst[ki] = (__bf16)W1[(size_t)(kbase + ki) * HIDDEN + n];
    } else if (i < 4608) {     // W2F[ks][t][lane][ki], n>=17 zero-padded
        int f = i - 4096;
        int lane = f & 63, t = (f >> 6) & 1, ks = f >> 7;
        int m = lane & 15, q = lane >> 4;
        int n = t * 16 + m;
        int kbase = ks * 32 + q * 8;
        __bf16* dst = w2f + (size_t)f * 8;
        #pragma unroll
        for (int ki = 0; ki < 8; ++ki)
            dst[ki] = (n < EDGE_DIM) ? (__bf16)W2[(size_t)(kbase + ki) * EDGE_DIM + n]
                                     : (__bf16)0.0f;
    }
}

__global__ void bucket_kernel(const int* __restrict__ idx,
                              int* __restrict__ counts, int* __restrict__ slots) {
    // int64 path: thread handles 2 connections via int4 loads
    int i = blockIdx.x * 256 + threadIdx.x;
    if (i >= NUM_CONN / 2) return;
    int4 vn = ((const int4*)idx)[i];                       // elems 2i, 2i+1 (lo,hi)
    int4 ve = ((const int4*)(idx + 2 * NUM_CONN))[i];      // elems NUM_CONN+2i, +1
    int p0 = atomicAdd(&counts[ve.x], 1);
    if (p0 < PAD) slots[(size_t)ve.x * PAD + p0] = vn.x;
    int p1 = atomicAdd(&counts[ve.z], 1);
    if (p1 < PAD) slots[(size_t)ve.z * PAD + p1] = vn.z;
}

__global__ void bucket_kernel_i32(const int* __restrict__ idx,
                                  int* __restrict__ counts, int* __restrict__ slots) {
    int i = blockIdx.x * 256 + threadIdx.x;
    if (i >= NUM_CONN) return;
    int node = idx[i];
    int edge = idx[NUM_CONN + i];
    int pos = atomicAdd(&counts[edge], 1);
    if (pos < PAD) slots[(size_t)edge * PAD + pos] = node;
}

// P[m][n] = sum_k nf[m][k] * W1[k][n]; 4 m-tiles/wave, 256 rows/block.
__global__ __launch_bounds__(256, 2) void proj_kernel(const float* __restrict__ nf,
                                                      const __bf16* __restrict__ w1f,
                                                      __bf16* __restrict__ pbf) {
    __shared__ __align__(16) __bf16 lds[32768];   // 64 KB, fragment-major
    {
        const uint4* s = (const uint4*)w1f;
        uint4* d = (uint4*)lds;
        #pragma unroll 4
        for (int i = threadIdx.x; i < 4096; i += 256) d[i] = s[i];
    }
    __syncthreads();

    const int wave = threadIdx.x >> 6;
    const int lane = threadIdx.x & 63;
    const int m = lane & 15, q = lane >> 4;
    const int rowbase = blockIdx.x * 256 + wave * 64;
    const bf16x8* frag = (const bf16x8*)lds;

    f32x4 acc[4][8];
    #pragma unroll
    for (int mt = 0; mt < 4; ++mt)
        #pragma unroll
        for (int t = 0; t < 8; ++t) acc[mt][t] = (f32x4){0.f, 0.f, 0.f, 0.f};

    const float* ap[4];
    #pragma unroll
    for (int mt = 0; mt < 4; ++mt) {
        int r = rowbase + mt * 16 + m;
        if (r >= NUM_NODES) r = NUM_NODES - 1;
        ap[mt] = nf + (size_t)r * IN_DIM + q * 8;
    }

    #pragma unroll
    for (int kc2 = 0; kc2 < 8; ++kc2) {
        bf16x8 b[8];
        #pragma unroll
        for (int t = 0; t < 8; ++t) b[t] = frag[(kc2 * 8 + t) * 64 + lane];
        #pragma unroll
        for (int mt = 0; mt < 4; ++mt) {
            float4 f0 = *(const float4*)(ap[mt] + kc2 * 32);
            float4 f1 = *(const float4*)(ap[mt] + kc2 * 32 + 4);
            bf16x8 a;
            a[0] = (__bf16)f0.x; a[1] = (__bf16)f0.y;
            a[2] = (__bf16)f0.z; a[3] = (__bf16)f0.w;
            a[4] = (__bf16)f1.x; a[5] = (__bf16)f1.y;
            a[6] = (__bf16)f1.z; a[7] = (__bf16)f1.w;
            #pragma unroll
            for (int t = 0; t < 8; ++t)
                acc[mt][t] = __builtin_amdgcn_mfma_f32_16x16x32_bf16(a, b[t], acc[mt][t], 0, 0, 0);
        }
    }

    #pragma unroll
    for (int mt = 0; mt < 4; ++mt) {
        int ob = rowbase + mt * 16 + q * 4;
        #pragma unroll
        for (int t = 0; t < 8; ++t)
            #pragma unroll
            for (int r = 0; r < 4; ++r) {
                int orow = ob + r;
                if (orow < NUM_NODES)
                    pbf[(size_t)orow * HIDDEN + t * 16 + m] = (__bf16)acc[mt][t][r];
            }
    }
}

// One wave per edge: gather-mean (2 rows per wave-load, uint2/lane), +b1, LN, ReLU,
// store r bf16. Lane owns hidden dims 4g..4g+3 where g = lane&31.
__global__ __launch_bounds__(256) void edge_kernel(const uint2* __restrict__ p2,
        const int* __restrict__ counts, const int* __restrict__ slots,
        const float* __restrict__ b1, const float* __restrict__ ln_g,
        const float* __restrict__ ln_b, uint2* __restrict__ rws) {
    const int wave = threadIdx.x >> 6;
    const int lane = threadIdx.x & 63;
    const int e = blockIdx.x * 4 + wave;
    const int g = lane & 31, hf = lane >> 5;

    const int c = counts[e];
    const int cc = c < PAD ? c : PAD;
    const float inv = 1.0f / (float)(c > 0 ? c : 1);
    const int* sl = slots + (size_t)e * PAD;

    float a0 = 0.f, a1 = 0.f, a2 = 0.f, a3 = 0.f;
    const int full = cc & ~7;
    for (int j = 0; j < full; j += 8) {            // unpredicated full batches
        int4 na = *(const int4*)(sl + j);
        int4 nb = *(const int4*)(sl + j + 4);
        int nd[8] = {na.x, na.y, na.z, na.w, nb.x, nb.y, nb.z, nb.w};
        uint2 u[4];
        #pragma unroll
        for (int k = 0; k < 4; ++k)
            u[k] = p2[(size_t)nd[2 * k + hf] * 32 + g];   // 8 rows via 4 loads/lane
        #pragma unroll
        for (int k = 0; k < 4; ++k) {
            a0 += __uint_as_float(u[k].x << 16);
            a1 += __uint_as_float(u[k].x & 0xffff0000u);
            a2 += __uint_as_float(u[k].y << 16);
            a3 += __uint_as_float(u[k].y & 0xffff0000u);
        }
    }
    if (full < cc) {                               // single predicated tail batch
        int4 na = *(const int4*)(sl + full);
        int4 nb = *(const int4*)(sl + full + 4);
        int nd[8] = {na.x, na.y, na.z, na.w, nb.x, nb.y, nb.z, nb.w};
        #pragma unroll
        for (int k = 0; k < 4; ++k) {
            int rj = full + 2 * k + hf;
            int n = nd[2 * k + hf];
            n = ((unsigned)n < NUM_NODES) ? n : 0;
            uint2 u = p2[(size_t)n * 32 + g];
            bool ok = rj < cc;
            a0 += ok ? __uint_as_float(u.x << 16) : 0.f;
            a1 += ok ? __uint_as_float(u.x & 0xffff0000u) : 0.f;
            a2 += ok ? __uint_as_float(u.y << 16) : 0.f;
            a3 += ok ? __uint_as_float(u.y & 0xffff0000u) : 0.f;
        }
    }
    // merge the two row-halves
    a0 += __shfl_xor(a0, 32, 64);
    a1 += __shfl_xor(a1, 32, 64);
    a2 += __shfl_xor(a2, 32, 64);
    a3 += __shfl_xor(a3, 32, 64);

    float4 b1v = ((const float4*)b1)[g];
    float h0 = a0 * inv + b1v.x;
    float h1 = a1 * inv + b1v.y;
    float h2 = a2 * inv + b1v.z;
    float h3 = a3 * inv + b1v.w;

    float s = h0 + h1 + h2 + h3;
    #pragma unroll
    for (int off = 16; off > 0; off >>= 1) s += __shfl_xor(s, off, 64);
    float mu = s * (1.0f / 128.0f);
    float d0 = h0 - mu, d1 = h1 - mu, d2 = h2 - mu, d3 = h3 - mu;
    float v = d0 * d0 + d1 * d1 + d2 * d2 + d3 * d3;
    #pragma unroll
    for (int off = 16; off > 0; off >>= 1) v += __shfl_xor(v, off, 64);
    float rs = rsqrtf(v * (1.0f / 128.0f) + 1e-5f);

    float4 gv = ((const float4*)ln_g)[g];
    float4 bv = ((const float4*)ln_b)[g];
    float r0 = d0 * rs * gv.x + bv.x; r0 = r0 > 0.f ? r0 : 0.f;
    float r1 = d1 * rs * gv.y + bv.y; r1 = r1 > 0.f ? r1 : 0.f;
    float r2 = d2 * rs * gv.z + bv.z; r2 = r2 > 0.f ? r2 : 0.f;
    float r3 = d3 * rs * gv.w + bv.w; r3 = r3 > 0.f ? r3 : 0.f;

    if (hf == 0) {
        union { __bf16 b[4]; uint2 u; } pk;
        pk.b[0] = (__bf16)r0; pk.b[1] = (__bf16)r1;
        pk.b[2] = (__bf16)r2; pk.b[3] = (__bf16)r3;
        rws[(size_t)e * 32 + g] = pk.u;
    }
}

// out[e][j] = r[e]·W2[:,j] + b2[j] via MFMA: [50K x 128] @ [128 x 32pad].
__global__ __launch_bounds__(256) void out_kernel(const __bf16* __restrict__ rws,
        const __bf16* __restrict__ w2f, const float* __restrict__ b2,
        float* __restrict__ out) {
    __shared__ __align__(16) __bf16 lds[4096];   // 8 KB
    {
        const uint4* s = (const uint4*)w2f;
        uint4* d = (uint4*)lds;
        #pragma unroll
        for (int i = threadIdx.x; i < 512; i += 256) d[i] = s[i];
    }
    __syncthreads();
    const int wave = threadIdx.x >> 6;
    const int lane = threadIdx.x & 63;
    const int tile = blockIdx.x * 4 + wave;
    if (tile >= NUM_EDGES / 16) return;
    const int m = lane & 15, q = lane >> 4;
    const bf16x8* frag = (const bf16x8*)lds;
    const __bf16* arow = rws + ((size_t)tile * 16 + m) * HIDDEN + q * 8;

    f32x4 acc0 = (f32x4){0.f, 0.f, 0.f, 0.f};
    f32x4 acc1 = (f32x4){0.f, 0.f, 0.f, 0.f};
    #pragma unroll
    for (int s = 0; s < 4; ++s) {
        bf16x8 a = *(const bf16x8*)(arow + s * 32);
        acc0 = __builtin_amdgcn_mfma_f32_16x16x32_bf16(a, frag[(s * 2 + 0) * 64 + lane], acc0, 0, 0, 0);
        acc1 = __builtin_amdgcn_mfma_f32_16x16x32_bf16(a, frag[(s * 2 + 1) * 64 + lane], acc1, 0, 0, 0);
    }
    int rowb = tile * 16 + q * 4;
    float bm = b2[m];
    #pragma unroll
    for (int r = 0; r < 4; ++r) {
        out[(size_t)(rowb + r) * EDGE_DIM + m] = acc0[r] + bm;
        if (m == 0) out[(size_t)(rowb + r) * EDGE_DIM + 16] = acc1[r] + b2[16];
    }
}

extern "C" void kernel_launch(void* const* d_in, const int* in_sizes, int n_in,
                              void* d_out, int out_size, void* d_ws, size_t ws_size,
                              hipStream_t stream) {
    const float* nf  = (const float*)d_in[0];
    const int*   idx = (const int*)d_in[1];
    const float* W1  = (const float*)d_in[2];
    const float* b1  = (const float*)d_in[3];
    const float* g   = (const float*)d_in[4];
    const float* be  = (const float*)d_in[5];
    const float* W2  = (const float*)d_in[6];
    const float* b2  = (const float*)d_in[7];
    float* out = (float*)d_out;

    char* ws = (char*)d_ws;
    __bf16* P      = (__bf16*)ws;
    int*    counts = (int*)(ws + 25600000);
    int*    slots  = (int*)(ws + 25800000);
    __bf16* W1F    = (__bf16*)(ws + 38600000);
    __bf16* W2F    = (__bf16*)(ws + 38665536);
    __bf16* R      = (__bf16*)(ws + 38673728);

    int stride = (in_sizes[1] == 2 * NUM_CONN) ? 1 : 2;

    hipMemsetAsync(counts, 0, (size_t)NUM_EDGES * 4, stream);
    pack_w_kernel<<<18, 256, 0, stream>>>(W1, W2, W1F, W2F);
    if (stride == 2)
        bucket_kernel<<<(NUM_CONN / 2 + 255) / 256, 256, 0, stream>>>(idx, counts, slots);
    else
        bucket_kernel_i32<<<(NUM_CONN + 255) / 256, 256, 0, stream>>>(idx, counts, slots);
    proj_kernel<<<(NUM_NODES + 255) / 256, 256, 0, stream>>>(nf, W1F, P);
    edge_kernel<<<NUM_EDGES / 4, 256, 0, stream>>>((const uint2*)P, counts, slots,
                                                   b1, g, be, (uint2*)R);
    out_kernel<<<(NUM_EDGES / 16 + 3) / 4, 256, 0, stream>>>(R, W2F, b2, out);
}

// Round 4
// 273.750 us; speedup vs baseline: 1.2454x; 1.0112x over previous
//
#include <hip/hip_runtime.h>
#include <hip/hip_bf16.h>
#include <stdint.h>

#define NUM_NODES 100000
#define NUM_EDGES 50000
#define NUM_CONN  800000
#define IN_DIM    256
#define HIDDEN    128
#define EDGE_DIM  17
#define PAD       64

typedef __bf16 bf16x8 __attribute__((ext_vector_type(8)));
typedef float  f32x4  __attribute__((ext_vector_type(4)));

// ---------------- ws layout ----------------
// P     : bf16 [NUM_NODES][HIDDEN]   25,600,000 B @ 0
// counts: int  [NUM_EDGES]              200,000 B @ 25,600,000
// slots : int  [NUM_EDGES][PAD]      12,800,000 B @ 25,800,000
// W1F   : bf16 frag-major [8][8][64][8]  65,536 B @ 38,600,000
// W2F   : bf16 frag-major [4][2][64][8]   8,192 B @ 38,665,536
// r     : bf16 [NUM_EDGES][HIDDEN]   12,800,000 B @ 38,673,728

// Zero counts + pack W1/W2 into MFMA B-fragment-major bf16 (one launch).
__global__ void prep_kernel(const float* __restrict__ W1, const float* __restrict__ W2,
                            __bf16* __restrict__ w1f, __bf16* __restrict__ w2f,
                            int* __restrict__ counts) {
    int i = blockIdx.x * 256 + threadIdx.x;   // grid 196*256 = 50176
    if (i < NUM_EDGES) counts[i] = 0;
    if (i < 4096) {            // W1F[kc2][t][lane][ki]
        int lane = i & 63, t = (i >> 6) & 7, kc2 = i >> 9;
        int m = lane & 15, q = lane >> 4;
        int n = t * 16 + m;
        int kbase = kc2 * 32 + q * 8;
        __bf16* dst = w1f + (size_t)i * 8;
        #pragma unroll
        for (int ki = 0; ki < 8; ++ki)
            dst[ki] = (__bf16)W1[(size_t)(kbase + ki) * HIDDEN + n];
    } else if (i < 4608) {     // W2F[ks][t][lane][ki], n>=17 zero-padded
        int f = i - 4096;
        int lane = f & 63, t = (f >> 6) & 1, ks = f >> 7;
        int m = lane & 15, q = lane >> 4;
        int n = t * 16 + m;
        int kbase = ks * 32 + q * 8;
        __bf16* dst = w2f + (size_t)f * 8;
        #pragma unroll
        for (int ki = 0; ki < 8; ++ki)
            dst[ki] = (n < EDGE_DIM) ? (__bf16)W2[(size_t)(kbase + ki) * EDGE_DIM + n]
                                     : (__bf16)0.0f;
    }
}

__global__ void bucket_kernel(const int* __restrict__ idx,
                              int* __restrict__ counts, int* __restrict__ slots) {
    // int64 path: thread handles 2 connections via int4 loads
    int i = blockIdx.x * 256 + threadIdx.x;
    if (i >= NUM_CONN / 2) return;
    int4 vn = ((const int4*)idx)[i];
    int4 ve = ((const int4*)(idx + 2 * NUM_CONN))[i];
    int p0 = atomicAdd(&counts[ve.x], 1);
    if (p0 < PAD) slots[(size_t)ve.x * PAD + p0] = vn.x;
    int p1 = atomicAdd(&counts[ve.z], 1);
    if (p1 < PAD) slots[(size_t)ve.z * PAD + p1] = vn.z;
}

__global__ void bucket_kernel_i32(const int* __restrict__ idx,
                                  int* __restrict__ counts, int* __restrict__ slots) {
    int i = blockIdx.x * 256 + threadIdx.x;
    if (i >= NUM_CONN) return;
    int node = idx[i];
    int edge = idx[NUM_CONN + i];
    int pos = atomicAdd(&counts[edge], 1);
    if (pos < PAD) slots[(size_t)edge * PAD + pos] = node;
}

// P[m][n] = sum_k nf[m][k] * W1[k][n]; 4 m-tiles/wave, 256 rows/block.
__global__ __launch_bounds__(256, 2) void proj_kernel(const float* __restrict__ nf,
                                                      const __bf16* __restrict__ w1f,
                                                      __bf16* __restrict__ pbf) {
    __shared__ __align__(16) __bf16 lds[32768];   // 64 KB, fragment-major
    {
        const uint4* s = (const uint4*)w1f;
        uint4* d = (uint4*)lds;
        #pragma unroll 4
        for (int i = threadIdx.x; i < 4096; i += 256) d[i] = s[i];
    }
    __syncthreads();

    const int wave = threadIdx.x >> 6;
    const int lane = threadIdx.x & 63;
    const int m = lane & 15, q = lane >> 4;
    const int rowbase = blockIdx.x * 256 + wave * 64;
    const bf16x8* frag = (const bf16x8*)lds;

    f32x4 acc[4][8];
    #pragma unroll
    for (int mt = 0; mt < 4; ++mt)
        #pragma unroll
        for (int t = 0; t < 8; ++t) acc[mt][t] = (f32x4){0.f, 0.f, 0.f, 0.f};

    const float* ap[4];
    #pragma unroll
    for (int mt = 0; mt < 4; ++mt) {
        int r = rowbase + mt * 16 + m;
        if (r >= NUM_NODES) r = NUM_NODES - 1;
        ap[mt] = nf + (size_t)r * IN_DIM + q * 8;
    }

    #pragma unroll
    for (int kc2 = 0; kc2 < 8; ++kc2) {
        bf16x8 b[8];
        #pragma unroll
        for (int t = 0; t < 8; ++t) b[t] = frag[(kc2 * 8 + t) * 64 + lane];
        #pragma unroll
        for (int mt = 0; mt < 4; ++mt) {
            float4 f0 = *(const float4*)(ap[mt] + kc2 * 32);
            float4 f1 = *(const float4*)(ap[mt] + kc2 * 32 + 4);
            bf16x8 a;
            a[0] = (__bf16)f0.x; a[1] = (__bf16)f0.y;
            a[2] = (__bf16)f0.z; a[3] = (__bf16)f0.w;
            a[4] = (__bf16)f1.x; a[5] = (__bf16)f1.y;
            a[6] = (__bf16)f1.z; a[7] = (__bf16)f1.w;
            #pragma unroll
            for (int t = 0; t < 8; ++t)
                acc[mt][t] = __builtin_amdgcn_mfma_f32_16x16x32_bf16(a, b[t], acc[mt][t], 0, 0, 0);
        }
    }

    #pragma unroll
    for (int mt = 0; mt < 4; ++mt) {
        int ob = rowbase + mt * 16 + q * 4;
        #pragma unroll
        for (int t = 0; t < 8; ++t)
            #pragma unroll
            for (int r = 0; r < 4; ++r) {
                int orow = ob + r;
                if (orow < NUM_NODES)
                    pbf[(size_t)orow * HIDDEN + t * 16 + m] = (__bf16)acc[mt][t][r];
            }
    }
}

// One wave per edge. Slots loaded once (sl[lane]) and distributed via shfl.
// Gather: uint4/lane, 16 lanes/row, 4 rows per wave-load, 16-row batches.
// Lane owns dims 8g..8g+7 (g = lane&15); rsel = lane>>4 picks row within quad.
__global__ __launch_bounds__(256) void edge_kernel(const uint4* __restrict__ p4,
        const int* __restrict__ counts, const int* __restrict__ slots,
        const float* __restrict__ b1, const float* __restrict__ ln_g,
        const float* __restrict__ ln_b, uint4* __restrict__ rws) {
    const int wave = threadIdx.x >> 6;
    const int lane = threadIdx.x & 63;
    const int e = blockIdx.x * 4 + wave;
    const int g = lane & 15, rsel = lane >> 4;

    const int c = counts[e];
    const int cc = c < PAD ? c : PAD;
    const float inv = 1.0f / (float)(c > 0 ? c : 1);
    const int slv = slots[(size_t)e * PAD + lane];   // all 64 slots, one load

    float acc[8];
    #pragma unroll
    for (int d = 0; d < 8; ++d) acc[d] = 0.f;

    for (int j0 = 0; j0 < cc; j0 += 16) {
        uint4 u[4];
        unsigned okm[4];
        #pragma unroll
        for (int qq = 0; qq < 4; ++qq) {
            int j = j0 + 4 * qq + rsel;
            int nd = __shfl(slv, j, 64);             // j < 64 always
            nd = ((unsigned)nd < NUM_NODES) ? nd : 0;
            u[qq] = p4[(size_t)nd * 16 + g];         // 4 loads in flight
            okm[qq] = (j < cc) ? 0xffffffffu : 0u;
        }
        #pragma unroll
        for (int qq = 0; qq < 4; ++qq) {
            uint4 v = u[qq];
            v.x &= okm[qq]; v.y &= okm[qq]; v.z &= okm[qq]; v.w &= okm[qq];
            acc[0] += __uint_as_float(v.x << 16);
            acc[1] += __uint_as_float(v.x & 0xffff0000u);
            acc[2] += __uint_as_float(v.y << 16);
            acc[3] += __uint_as_float(v.y & 0xffff0000u);
            acc[4] += __uint_as_float(v.z << 16);
            acc[5] += __uint_as_float(v.z & 0xffff0000u);
            acc[6] += __uint_as_float(v.w << 16);
            acc[7] += __uint_as_float(v.w & 0xffff0000u);
        }
    }
    // merge the 4 rsel groups (lanes differing in bits 4-5)
    #pragma unroll
    for (int d = 0; d < 8; ++d) {
        acc[d] += __shfl_xor(acc[d], 16, 64);
        acc[d] += __shfl_xor(acc[d], 32, 64);
    }

    float4 bA = ((const float4*)b1)[2 * g];
    float4 bB = ((const float4*)b1)[2 * g + 1];
    float h[8];
    h[0] = acc[0] * inv + bA.x; h[1] = acc[1] * inv + bA.y;
    h[2] = acc[2] * inv + bA.z; h[3] = acc[3] * inv + bA.w;
    h[4] = acc[4] * inv + bB.x; h[5] = acc[5] * inv + bB.y;
    h[6] = acc[6] * inv + bB.z; h[7] = acc[7] * inv + bB.w;

    float s = 0.f;
    #pragma unroll
    for (int d = 0; d < 8; ++d) s += h[d];
    #pragma unroll
    for (int off = 8; off > 0; off >>= 1) s += __shfl_xor(s, off, 64);
    float mu = s * (1.0f / 128.0f);

    float dv[8], vv = 0.f;
    #pragma unroll
    for (int d = 0; d < 8; ++d) { dv[d] = h[d] - mu; vv += dv[d] * dv[d]; }
    #pragma unroll
    for (int off = 8; off > 0; off >>= 1) vv += __shfl_xor(vv, off, 64);
    float rs = rsqrtf(vv * (1.0f / 128.0f) + 1e-5f);

    float4 gA = ((const float4*)ln_g)[2 * g];
    float4 gB = ((const float4*)ln_g)[2 * g + 1];
    float4 eA = ((const float4*)ln_b)[2 * g];
    float4 eB = ((const float4*)ln_b)[2 * g + 1];
    float gg[8] = {gA.x, gA.y, gA.z, gA.w, gB.x, gB.y, gB.z, gB.w};
    float ee[8] = {eA.x, eA.y, eA.z, eA.w, eB.x, eB.y, eB.z, eB.w};
    if (rsel == 0) {
        union { __bf16 b[8]; uint4 u; } pk;
        #pragma unroll
        for (int d = 0; d < 8; ++d) {
            float r = dv[d] * rs * gg[d] + ee[d];
            pk.b[d] = (__bf16)(r > 0.f ? r : 0.f);
        }
        rws[(size_t)e * 16 + g] = pk.u;
    }
}

// out[e][j] = r[e]·W2[:,j] + b2[j] via MFMA: [50K x 128] @ [128 x 32pad].
__global__ __launch_bounds__(256) void out_kernel(const __bf16* __restrict__ rws,
        const __bf16* __restrict__ w2f, const float* __restrict__ b2,
        float* __restrict__ out) {
    __shared__ __align__(16) __bf16 lds[4096];   // 8 KB
    {
        const uint4* s = (const uint4*)w2f;
        uint4* d = (uint4*)lds;
        #pragma unroll
        for (int i = threadIdx.x; i < 512; i += 256) d[i] = s[i];
    }
    __syncthreads();
    const int wave = threadIdx.x >> 6;
    const int lane = threadIdx.x & 63;
    const int tile = blockIdx.x * 4 + wave;
    if (tile >= NUM_EDGES / 16) return;
    const int m = lane & 15, q = lane >> 4;
    const bf16x8* frag = (const bf16x8*)lds;
    const __bf16* arow = rws + ((size_t)tile * 16 + m) * HIDDEN + q * 8;

    f32x4 acc0 = (f32x4){0.f, 0.f, 0.f, 0.f};
    f32x4 acc1 = (f32x4){0.f, 0.f, 0.f, 0.f};
    #pragma unroll
    for (int s = 0; s < 4; ++s) {
        bf16x8 a = *(const bf16x8*)(arow + s * 32);
        acc0 = __builtin_amdgcn_mfma_f32_16x16x32_bf16(a, frag[(s * 2 + 0) * 64 + lane], acc0, 0, 0, 0);
        acc1 = __builtin_amdgcn_mfma_f32_16x16x32_bf16(a, frag[(s * 2 + 1) * 64 + lane], acc1, 0, 0, 0);
    }
    int rowb = tile * 16 + q * 4;
    float bm = b2[m];
    #pragma unroll
    for (int r = 0; r < 4; ++r) {
        out[(size_t)(rowb + r) * EDGE_DIM + m] = acc0[r] + bm;
        if (m == 0) out[(size_t)(rowb + r) * EDGE_DIM + 16] = acc1[r] + b2[16];
    }
}

extern "C" void kernel_launch(void* const* d_in, const int* in_sizes, int n_in,
                              void* d_out, int out_size, void* d_ws, size_t ws_size,
                              hipStream_t stream) {
    const float* nf  = (const float*)d_in[0];
    const int*   idx = (const int*)d_in[1];
    const float* W1  = (const float*)d_in[2];
    const float* b1  = (const float*)d_in[3];
    const float* g   = (const float*)d_in[4];
    const float* be  = (const float*)d_in[5];
    const float* W2  = (const float*)d_in[6];
    const float* b2  = (const float*)d_in[7];
    float* out = (float*)d_out;

    char* ws = (char*)d_ws;
    __bf16* P      = (__bf16*)ws;
    int*    counts = (int*)(ws + 25600000);
    int*    slots  = (int*)(ws + 25800000);
    __bf16* W1F    = (__bf16*)(ws + 38600000);
    __bf16* W2F    = (__bf16*)(ws + 38665536);
    __bf16* R      = (__bf16*)(ws + 38673728);

    int stride = (in_sizes[1] == 2 * NUM_CONN) ? 1 : 2;

    prep_kernel<<<196, 256, 0, stream>>>(W1, W2, W1F, W2F, counts);
    if (stride == 2)
        bucket_kernel<<<(NUM_CONN / 2 + 255) / 256, 256, 0, stream>>>(idx, counts, slots);
    else
        bucket_kernel_i32<<<(NUM_CONN + 255) / 256, 256, 0, stream>>>(idx, counts, slots);
    proj_kernel<<<(NUM_NODES + 255) / 256, 256, 0, stream>>>(nf, W1F, P);
    edge_kernel<<<NUM_EDGES / 4, 256, 0, stream>>>((const uint4*)P, counts, slots,
                                                   b1, g, be, (uint4*)R);
    out_kernel<<<(NUM_EDGES / 16 + 3) / 4, 256, 0, stream>>>(R, W2F, b2, out);
}